// Round 1
// baseline (188.963 us; speedup 1.0000x reference)
//
#include <hip/hip_runtime.h>
#include <hip/hip_bf16.h>
#include <cstdint>
#include <cstddef>

typedef __attribute__((ext_vector_type(8))) short bf16x8;
typedef __attribute__((ext_vector_type(4))) float f32x4;

constexpr int Bc = 2, Sc = 2048, Dc = 512, Hc = 8, DKc = 64;

struct alignas(16) us8 { unsigned short u[8]; };

__device__ __forceinline__ unsigned short f2bf(float x) {
  union { float f; unsigned int u; } v; v.f = x;
  unsigned int r = (v.u + 0x7FFFu + ((v.u >> 16) & 1u)) >> 16;
  return (unsigned short)r;
}

__device__ __forceinline__ us8 cvt8(float4 a, float4 b) {
  us8 o;
  o.u[0] = f2bf(a.x); o.u[1] = f2bf(a.y); o.u[2] = f2bf(a.z); o.u[3] = f2bf(a.w);
  o.u[4] = f2bf(b.x); o.u[5] = f2bf(b.y); o.u[6] = f2bf(b.z); o.u[7] = f2bf(b.w);
  return o;
}

// C = A * W^T + bias.  A: [M,K] (fp32 or bf16), W: [N,K] fp32 (converted to bf16 in staging).
// OUT_MODE 0: bf16 row-major [M,N]; 1: bf16 transposed per batch -> [b][n][s] (V^T); 2: fp32 [M,N].
template<int A_BF16, int OUT_MODE>
__global__ __launch_bounds__(256)
void gemm_nt(const void* __restrict__ Ap, const float* __restrict__ Wp,
             const float* __restrict__ bias, void* __restrict__ Cp,
             int M, int N, int K)
{
  constexpr int KC = 32;
  __shared__ unsigned short As[64][KC + 8];
  __shared__ unsigned short Bs[64][KC + 8];
  const int tid = threadIdx.x;
  const int lane = tid & 63, wid = tid >> 6;
  const int m0 = blockIdx.x * 64, n0 = blockIdx.y * 64;

  f32x4 acc[4] = {{0,0,0,0},{0,0,0,0},{0,0,0,0},{0,0,0,0}};

  const int r = tid >> 2;
  const int c = (tid & 3) * 8;

  for (int k0 = 0; k0 < K; k0 += KC) {
    __syncthreads();
    if (A_BF16) {
      const unsigned short* A = (const unsigned short*)Ap;
      *(us8*)&As[r][c] = *(const us8*)(A + (size_t)(m0 + r) * K + k0 + c);
    } else {
      const float* A = (const float*)Ap;
      const float* p = A + (size_t)(m0 + r) * K + k0 + c;
      float4 v0 = *(const float4*)p, v1 = *(const float4*)(p + 4);
      *(us8*)&As[r][c] = cvt8(v0, v1);
    }
    {
      const float* p = Wp + (size_t)(n0 + r) * K + k0 + c;
      float4 v0 = *(const float4*)p, v1 = *(const float4*)(p + 4);
      *(us8*)&Bs[r][c] = cvt8(v0, v1);
    }
    __syncthreads();
    bf16x8 af = *(const bf16x8*)&As[wid * 16 + (lane & 15)][(lane >> 4) * 8];
#pragma unroll
    for (int n = 0; n < 4; ++n) {
      bf16x8 bfv = *(const bf16x8*)&Bs[n * 16 + (lane & 15)][(lane >> 4) * 8];
      acc[n] = __builtin_amdgcn_mfma_f32_16x16x32_bf16(af, bfv, acc[n], 0, 0, 0);
    }
  }

  const int colb = lane & 15;
  const int rowb = (lane >> 4) * 4;
#pragma unroll
  for (int n = 0; n < 4; ++n) {
    const int gn = n0 + n * 16 + colb;
    const float bv = bias[gn];
#pragma unroll
    for (int rr = 0; rr < 4; ++rr) {
      const int gm = m0 + wid * 16 + rowb + rr;
      const float y = acc[n][rr] + bv;
      if (OUT_MODE == 0) {
        ((unsigned short*)Cp)[(size_t)gm * N + gn] = f2bf(y);
      } else if (OUT_MODE == 1) {
        const int bb = gm >> 11, ss = gm & (Sc - 1);
        ((unsigned short*)Cp)[((size_t)bb * N + gn) * Sc + ss] = f2bf(y);
      } else {
        ((float*)Cp)[(size_t)gm * N + gn] = y;
      }
    }
  }
}

// Flash-style attention for one (b,h) and a 64-row q tile.
// Qb,Kb: bf16 [B,S,D]; Vt: bf16 [B,D,S]; Gp: fp32 [B,S,S]; Mp: int [B,S,S];
// Xb out: bf16 [B,S,D].
__global__ __launch_bounds__(256)
void attn_kernel(const unsigned short* __restrict__ Qb,
                 const unsigned short* __restrict__ Kb,
                 const unsigned short* __restrict__ Vt,
                 const float* __restrict__ Gp,
                 const int* __restrict__ Mp,
                 unsigned short* __restrict__ Xb)
{
  __shared__ unsigned short Qs[64][72];
  __shared__ unsigned short Ks[64][72];
  __shared__ unsigned short Vs[64][72];   // [dk][kc]
  __shared__ float Gs[64][68];
  __shared__ float Ms[64][68];
  __shared__ unsigned short Ps[4][16][72];

  const int tid = threadIdx.x, lane = tid & 63, wid = tid >> 6;
  const int bh = blockIdx.x, b = bh >> 3, h = bh & 7;
  const int q0 = blockIdx.y * 64;

  const int r = tid >> 2;            // 0..63
  const int c = (tid & 3) * 16;      // 0,16,32,48

  {
    const unsigned short* qp = Qb + ((size_t)(b * Sc + q0 + r) * Dc + h * DKc + c);
    *(us8*)&Qs[r][c]     = *(const us8*)qp;
    *(us8*)&Qs[r][c + 8] = *(const us8*)(qp + 8);
  }

  f32x4 acc[4] = {{0,0,0,0},{0,0,0,0},{0,0,0,0},{0,0,0,0}};
  float mrun[4] = {-1e30f, -1e30f, -1e30f, -1e30f};
  float lrun[4] = {0.f, 0.f, 0.f, 0.f};

  const int colb = lane & 15;
  const int rowb = (lane >> 4) * 4;

  for (int kt = 0; kt < Sc / 64; ++kt) {
    const int k0 = kt * 64;
    __syncthreads();
    {
      const unsigned short* kp = Kb + ((size_t)(b * Sc + k0 + r) * Dc + h * DKc + c);
      *(us8*)&Ks[r][c]     = *(const us8*)kp;
      *(us8*)&Ks[r][c + 8] = *(const us8*)(kp + 8);
      const unsigned short* vp = Vt + ((size_t)(b * Dc + h * DKc + r) * Sc + k0 + c);
      *(us8*)&Vs[r][c]     = *(const us8*)vp;
      *(us8*)&Vs[r][c + 8] = *(const us8*)(vp + 8);
      const float* gp = Gp + ((size_t)(b * Sc + q0 + r) * Sc + k0 + c);
#pragma unroll
      for (int j = 0; j < 4; ++j)
        *(float4*)&Gs[r][c + j * 4] = *(const float4*)(gp + j * 4);
      const int* mp = Mp + ((size_t)(b * Sc + q0 + r) * Sc + k0 + c);
#pragma unroll
      for (int j = 0; j < 4; ++j) {
        int4 mv = *(const int4*)(mp + j * 4);
        Ms[r][c + j * 4 + 0] = (float)mv.x;
        Ms[r][c + j * 4 + 1] = (float)mv.y;
        Ms[r][c + j * 4 + 2] = (float)mv.z;
        Ms[r][c + j * 4 + 3] = (float)mv.w;
      }
    }
    __syncthreads();

    // S = Q K^T  (A rows = q, B rows = kc, reduce over dk=64)
    f32x4 sf[4] = {{0,0,0,0},{0,0,0,0},{0,0,0,0},{0,0,0,0}};
#pragma unroll
    for (int kk = 0; kk < 2; ++kk) {
      bf16x8 af = *(const bf16x8*)&Qs[wid * 16 + colb][kk * 32 + (lane >> 4) * 8];
#pragma unroll
      for (int n = 0; n < 4; ++n) {
        bf16x8 bfv = *(const bf16x8*)&Ks[n * 16 + colb][kk * 32 + (lane >> 4) * 8];
        sf[n] = __builtin_amdgcn_mfma_f32_16x16x32_bf16(af, bfv, sf[n], 0, 0, 0);
      }
    }
    // scale + mask (allowed = mask||diag)
#pragma unroll
    for (int n = 0; n < 4; ++n) {
#pragma unroll
      for (int rr = 0; rr < 4; ++rr) {
        const int qi = wid * 16 + rowb + rr;
        const int kj = n * 16 + colb;
        float sv = sf[n][rr] * 0.125f;
        const bool allowed = (Ms[qi][kj] != 0.f) || (q0 + qi == k0 + kj);
        sf[n][rr] = allowed ? sv : -1e30f;
      }
    }
    // online softmax stats (rows live in 16-lane shuffle groups)
    float mnew[4], alpha[4], rsum[4];
#pragma unroll
    for (int rr = 0; rr < 4; ++rr) {
      float tm = fmaxf(fmaxf(sf[0][rr], sf[1][rr]), fmaxf(sf[2][rr], sf[3][rr]));
      tm = fmaxf(tm, __shfl_xor(tm, 1));
      tm = fmaxf(tm, __shfl_xor(tm, 2));
      tm = fmaxf(tm, __shfl_xor(tm, 4));
      tm = fmaxf(tm, __shfl_xor(tm, 8));
      const float mn = fmaxf(mrun[rr], tm);
      mnew[rr] = mn;
      alpha[rr] = __expf(mrun[rr] - mn);
      mrun[rr] = mn;
      rsum[rr] = 0.f;
    }
    // p = exp(s - m); l += p; Ps = bf16(p * g)
#pragma unroll
    for (int n = 0; n < 4; ++n) {
#pragma unroll
      for (int rr = 0; rr < 4; ++rr) {
        const int qi = wid * 16 + rowb + rr;
        const int kj = n * 16 + colb;
        const float p = __expf(sf[n][rr] - mnew[rr]);
        rsum[rr] += p;
        const float pg = p * Gs[qi][kj];
        Ps[wid][rowb + rr][kj] = f2bf(pg);
      }
    }
#pragma unroll
    for (int rr = 0; rr < 4; ++rr) {
      float s = rsum[rr];
      s += __shfl_xor(s, 1);
      s += __shfl_xor(s, 2);
      s += __shfl_xor(s, 4);
      s += __shfl_xor(s, 8);
      lrun[rr] = lrun[rr] * alpha[rr] + s;
    }
    __syncthreads();   // Ps write -> frag read ordering (uniform across waves)

    // acc = acc*alpha + (P*g) @ V
#pragma unroll
    for (int n = 0; n < 4; ++n)
#pragma unroll
      for (int rr = 0; rr < 4; ++rr) acc[n][rr] *= alpha[rr];
#pragma unroll
    for (int kk = 0; kk < 2; ++kk) {
      bf16x8 af = *(const bf16x8*)&Ps[wid][colb][kk * 32 + (lane >> 4) * 8];
#pragma unroll
      for (int n = 0; n < 4; ++n) {
        bf16x8 bfv = *(const bf16x8*)&Vs[n * 16 + colb][kk * 32 + (lane >> 4) * 8];
        acc[n] = __builtin_amdgcn_mfma_f32_16x16x32_bf16(af, bfv, acc[n], 0, 0, 0);
      }
    }
  }

  // epilogue: x = acc / l  -> bf16 [B,S,D]
#pragma unroll
  for (int n = 0; n < 4; ++n) {
#pragma unroll
    for (int rr = 0; rr < 4; ++rr) {
      const int qi = wid * 16 + rowb + rr;
      const float y = acc[n][rr] / lrun[rr];
      Xb[(size_t)(b * Sc + q0 + qi) * Dc + h * DKc + n * 16 + colb] = f2bf(y);
    }
  }
}

extern "C" void kernel_launch(void* const* d_in, const int* in_sizes, int n_in,
                              void* d_out, int out_size, void* d_ws, size_t ws_size,
                              hipStream_t stream)
{
  const float* query = (const float*)d_in[0];
  const float* key_  = (const float*)d_in[1];
  const float* value = (const float*)d_in[2];
  const float* gprob = (const float*)d_in[3];
  const int*   mask  = (const int*)d_in[4];
  const float* Wq = (const float*)d_in[5];
  const float* bq = (const float*)d_in[6];
  const float* Wk = (const float*)d_in[7];
  const float* bk = (const float*)d_in[8];
  const float* Wv = (const float*)d_in[9];
  const float* bv = (const float*)d_in[10];
  const float* Wo = (const float*)d_in[11];
  const float* bo = (const float*)d_in[12];
  float* out = (float*)d_out;

  const size_t elems = (size_t)Bc * Sc * Dc;   // 2*2048*512
  unsigned short* Qb = (unsigned short*)d_ws;
  unsigned short* Kb = Qb + elems;
  unsigned short* Vt = Kb + elems;
  unsigned short* Xb = Vt + elems;

  const int M = Bc * Sc, N = Dc, K = Dc;
  dim3 gg(M / 64, N / 64), blk(256);

  hipLaunchKernelGGL((gemm_nt<0, 0>), gg, blk, 0, stream, (const void*)query, Wq, bq, (void*)Qb, M, N, K);
  hipLaunchKernelGGL((gemm_nt<0, 0>), gg, blk, 0, stream, (const void*)key_,  Wk, bk, (void*)Kb, M, N, K);
  hipLaunchKernelGGL((gemm_nt<0, 1>), gg, blk, 0, stream, (const void*)value, Wv, bv, (void*)Vt, M, N, K);

  dim3 ga(Bc * Hc, Sc / 64);
  hipLaunchKernelGGL(attn_kernel, ga, blk, 0, stream, Qb, Kb, Vt, gprob, mask, Xb);

  hipLaunchKernelGGL((gemm_nt<1, 2>), gg, blk, 0, stream, (const void*)Xb, Wo, bo, (void*)out, M, N, K);
}